// Round 8
// baseline (18695.117 us; speedup 1.0000x reference)
//
#include <hip/hip_runtime.h>
#include <math.h>

#define NBLK 512
#define NTHR 256

typedef float f32x4 __attribute__((ext_vector_type(4)));

// ---------------- coherent (cross-XCD, L2-bypass) access helpers ----------------
__device__ __forceinline__ float2 ld2a(const float* p){
    unsigned long long u = __hip_atomic_load((const unsigned long long*)p,
                                             __ATOMIC_RELAXED, __HIP_MEMORY_SCOPE_AGENT);
    float2 r;
    r.x = __uint_as_float((unsigned)u);
    r.y = __uint_as_float((unsigned)(u >> 32));
    return r;
}
__device__ __forceinline__ void st2a(float* p, float a, float b){
    unsigned long long u = (unsigned long long)__float_as_uint(a)
                         | ((unsigned long long)__float_as_uint(b) << 32);
    __hip_atomic_store((unsigned long long*)p, u,
                       __ATOMIC_RELAXED, __HIP_MEMORY_SCOPE_AGENT);
}
__device__ __forceinline__ float ld1a(const float* p){
    unsigned u = __hip_atomic_load((const unsigned*)p, __ATOMIC_RELAXED, __HIP_MEMORY_SCOPE_AGENT);
    return __uint_as_float(u);
}
__device__ __forceinline__ void st1a(float* p, float v){
    __hip_atomic_store((unsigned*)p, __float_as_uint(v), __ATOMIC_RELAXED, __HIP_MEMORY_SCOPE_AGENT);
}

__device__ __forceinline__ float fsigmoid(float x){ return 1.0f/(1.0f + __expf(-x)); }
__device__ __forceinline__ float ftanh(float x){
    float e = __expf(2.0f*x);          // inf-safe
    return 1.0f - 2.0f/(e + 1.0f);
}
__device__ __forceinline__ float dot4(f32x4 a, f32x4 b){
    return a.x*b.x + a.y*b.y + a.z*b.z + a.w*b.w;
}

struct Params {
    const float* input_p; const float* mask_p; const float* input_q; const float* mask_q;
    const float* W_ih; const float* W_hh; const float* bias;
    const float* ln_i_g; const float* ln_i_b; const float* ln_h_g; const float* ln_h_b;
    const float* ln_c_g; const float* ln_c_b;
    const float* Wq; const float* Wp; const float* Wr; const float* w_att; const float* b_att;
    float* out;
    float* qWq;    // [2][2048][768] f32, read-only in coop
    float* iqT;    // [16][768][128] f32, read-only
    float* pWp0;   // [b*128+t][768]  = input_p @ Wp[0], read-only
    float* pWih0;  // [b*128+t][3072] = input_p @ W_ih[0][:768], read-only
    float* h;      // [2][16][768] coherent
    float* c;      // coherent (contiguous after h)
    float* sP;     // [8][16][768] coherent (0-3: h@Wr ; 4-7: cur@Wp d=1)
    float* whP;    // [4][16][3072]
    float* cwP;    // [4][16][3072]
    float* wiP;    // [4][16][3072]
    float* wghtd;  // [16][768]
    float* escore; // [16][128]
    unsigned* bar;
};

// ------------- monotonic tree barrier (512 blocks = 32 leaves x 16) -------------
__device__ __forceinline__ void gsync(unsigned* bar, int bid, unsigned n){
    __syncthreads();
    if (threadIdx.x == 0){
        unsigned* leaf = bar + 128 + (bid >> 4)*32;
        unsigned old = __hip_atomic_fetch_add(leaf, 1u, __ATOMIC_RELAXED, __HIP_MEMORY_SCOPE_AGENT);
        if ((old & 15u) == 15u){
            unsigned rold = __hip_atomic_fetch_add(bar + 32, 1u, __ATOMIC_RELAXED, __HIP_MEMORY_SCOPE_AGENT);
            if ((rold & 31u) == 31u){
                __hip_atomic_store(bar, n + 1u, __ATOMIC_RELEASE, __HIP_MEMORY_SCOPE_AGENT);
            }
        }
        int spins = 0;
        while (__hip_atomic_load(bar, __ATOMIC_RELAXED, __HIP_MEMORY_SCOPE_AGENT) < n + 1u){
            __builtin_amdgcn_s_sleep(4);
            if (++spins > 1024){
                (void)__hip_atomic_load(bar, __ATOMIC_ACQUIRE, __HIP_MEMORY_SCOPE_AGENT);
                spins = 0;
            }
        }
    }
    __syncthreads();
}

// stage A[16][192] f32 slice into LDS (coherent or plain source)
__device__ __forceinline__ void stageA(
    const float* Aptr, int ars, int aco, int k0, bool coh, float* Ash, int tid)
{
    #pragma unroll
    for (int rep = 0; rep < 6; rep++){
        int i2 = tid + rep*256;                  // 1536 f2 chunks (16 rows x 96)
        int r = i2 / 96, kk = (i2 % 96)*2;
        const float* src = Aptr + (size_t)r*ars + aco + k0 + kk;
        float2 v;
        if (coh) v = ld2a(src); else v = *(const float2*)src;
        Ash[r*192 + kk]     = v.x;
        Ash[r*192 + kk + 1] = v.y;
    }
    __syncthreads();
}

// f32-weight tile matmul: out[16][cbase..cbase+63] partial over k0..k0+191.
// thread: 1 row x 4 cols; double-buffered 8-k-deep f32x4 bursts (software pipeline).
__device__ __forceinline__ void mm192f(
    const float* W, int N, float* outP, int cbase, int k0,
    const float* Ash, int tid)
{
    int cg = tid & 15, rg = tid >> 4;
    int col = cbase + cg*4;
    const float* Wc = W + (size_t)k0*N + col;
    const float* Arow = Ash + rg*192;
    f32x4 acc = {0,0,0,0};
    f32x4 wA[8], wB[8];
    #pragma unroll
    for (int j = 0; j < 8; j++) wA[j] = *(const f32x4*)(Wc + (size_t)j*N);
    for (int kb = 0; kb < 192; kb += 16){
        #pragma unroll
        for (int j = 0; j < 8; j++) wB[j] = *(const f32x4*)(Wc + (size_t)(kb+8+j)*N);
        #pragma unroll
        for (int j = 0; j < 8; j++) acc += Arow[kb+j]*wA[j];
        if (kb < 176){
            #pragma unroll
            for (int j = 0; j < 8; j++) wA[j] = *(const f32x4*)(Wc + (size_t)(kb+16+j)*N);
        }
        #pragma unroll
        for (int j = 0; j < 8; j++) acc += Arow[kb+8+j]*wB[j];
    }
    float* o = outP + (size_t)rg*N + col;
    st2a(o,   acc.x, acc.y);
    st2a(o+2, acc.z, acc.w);
}

__device__ __forceinline__ float bsum4(float v, float* red, int tid){
    #pragma unroll
    for (int off = 32; off; off >>= 1) v += __shfl_xor(v, off);
    __syncthreads();
    if ((tid & 63) == 0) red[tid >> 6] = v;
    __syncthreads();
    float s = red[0]+red[1]+red[2]+red[3];
    __syncthreads();
    return s;
}

__global__ __launch_bounds__(NTHR, 2) void coop_kernel(Params p)
{
    __shared__ float smem[6936];
    const int tid = threadIdx.x;
    const int bid = blockIdx.x;
    unsigned n = 0;

    {
        int gid = bid*NTHR + tid;
        if (gid < 24576) st2a(p.h + gid*2, 0.f, 0.f);   // h then c, contiguous
        if (gid < 2048)  p.out[(size_t)16*128*768 + gid] = p.mask_p[gid];
    }
    gsync(p.bar, bid, n); n++;

    for (int t = 0; t < 128; ++t){
        for (int d = 0; d < 2; ++d){
            const float* h_d = p.h + (size_t)d*12288;

            // ===== S1: h/cur weight matmuls (64-col tiles x 4 k-chunks) =====
            // d=0: 60 tiles (12 Wr + 48 Whh)                         -> 240 blocks
            // d=1: 120 tiles (12 Wr + 12 Wp + 48 Whh + 48 Wih_cur)   -> 480 blocks
            {
                int ntile = (d == 0) ? 60 : 120;
                if (bid < ntile*4){
                    int tile = bid >> 2, kc = bid & 3, k0 = kc*192;
                    if (d == 0){
                        stageA(h_d, 768, 0, k0, true, smem, tid);
                        if (tile < 12){
                            mm192f(p.Wr, 768, p.sP + (size_t)kc*12288, tile*64, k0, smem, tid);
                        } else {
                            mm192f(p.W_hh, 3072, p.whP + (size_t)kc*49152, (tile-12)*64, k0, smem, tid);
                        }
                    } else {
                        bool useCur = (tile >= 12 && tile < 24) || (tile >= 72);
                        stageA(useCur ? p.h : h_d, 768, 0, k0, true, smem, tid);
                        if (tile < 12){
                            mm192f(p.Wr + (size_t)589824, 768,
                                   p.sP + (size_t)kc*12288, tile*64, k0, smem, tid);
                        } else if (tile < 24){
                            mm192f(p.Wp + (size_t)589824, 768,
                                   p.sP + (size_t)(4+kc)*12288, (tile-12)*64, k0, smem, tid);
                        } else if (tile < 72){
                            mm192f(p.W_hh + (size_t)2359296, 3072,
                                   p.whP + (size_t)kc*49152, (tile-24)*64, k0, smem, tid);
                        } else {
                            mm192f(p.W_ih + (size_t)4718592, 3072,
                                   p.cwP + (size_t)kc*49152, (tile-72)*64, k0, smem, tid);
                        }
                    }
                }
            }
            gsync(p.bar, bid, n); n++;

            // ===== S2a: scores (256 blocks: 16 per batch, 8 scores each) =====
            if (bid < 256){
                int b = bid >> 4, sq0 = (bid & 15)*8;
                float* s_sh  = smem;
                float* wa_sh = smem + 768;
                if (tid < 192){
                    f32x4 acc = *(const f32x4*)(p.b_att + d*768 + tid*4);
                    if (d == 0){
                        f32x4 pv = *(const f32x4*)(p.pWp0 + ((size_t)b*128 + t)*768 + tid*4);
                        acc += pv;
                    }
                    int ncp = (d == 0) ? 4 : 8;
                    for (int cp = 0; cp < ncp; cp++){
                        const float* src = p.sP + (size_t)cp*12288 + b*768 + tid*4;
                        float2 u0 = ld2a(src);
                        float2 u1 = ld2a(src + 2);
                        acc.x += u0.x; acc.y += u0.y; acc.z += u1.x; acc.w += u1.y;
                    }
                    *(f32x4*)&s_sh[tid*4] = acc;
                } else {
                    int i0 = tid - 192;
                    for (int r = 0; r < 3; r++){
                        int i = i0 + r*64;
                        *(f32x4*)&wa_sh[i*4] = *(const f32x4*)(p.w_att + d*768 + i*4);
                    }
                }
                __syncthreads();
                int sq = sq0 + (tid >> 5), l = tid & 31;
                const float* qrow = p.qWq + ((size_t)(d*2048 + b*128 + sq))*768;
                float part = 0.f;
                #pragma unroll
                for (int i = 0; i < 6; i++){
                    int a = i*128 + l*4;
                    f32x4 q  = *(const f32x4*)(qrow + a);
                    f32x4 s4 = *(const f32x4*)(s_sh + a);
                    f32x4 w4 = *(const f32x4*)(wa_sh + a);
                    part += ftanh(q.x + s4.x)*w4.x + ftanh(q.y + s4.y)*w4.y
                          + ftanh(q.z + s4.z)*w4.z + ftanh(q.w + s4.w)*w4.w;
                }
                #pragma unroll
                for (int off = 16; off; off >>= 1) part += __shfl_xor(part, off, 32);
                if (l == 0){
                    float e = (p.mask_q[b*128 + sq] > 0.f) ? __expf(part) : 0.f;
                    st1a(p.escore + b*128 + sq, e);
                }
            }
            gsync(p.bar, bid, n); n++;

            // ===== S2b: weighted (64 blocks) =====
            if (bid < 64){
                int b = bid >> 2, cg = bid & 3;
                float* e_sh = smem;    // 129
                if (tid < 128) e_sh[tid] = ld1a(p.escore + b*128 + tid);
                __syncthreads();
                if (tid < 64){
                    float v = e_sh[tid] + e_sh[tid + 64];
                    #pragma unroll
                    for (int off = 32; off; off >>= 1) v += __shfl_xor(v, off);
                    if (tid == 0) e_sh[128] = 1.0f / v;
                }
                __syncthreads();
                float inv = e_sh[128];
                if (tid < 192){
                    int cc = cg*192 + tid;
                    const float* ip = p.iqT + ((size_t)b*768 + cc)*128;
                    float acc = 0.f;
                    #pragma unroll 8
                    for (int j = 0; j < 32; j++){
                        f32x4 q  = *(const f32x4*)(ip + j*4);
                        f32x4 e4 = *(const f32x4*)&e_sh[j*4];
                        acc += dot4(q, e4);
                    }
                    st1a(p.wghtd + b*768 + cc, acc*inv);
                }
            }
            gsync(p.bar, bid, n); n++;

            // ===== S3: wi matmul (48 tiles x 4 kc = 192 blocks) =====
            if (bid < 192){
                int tile = bid >> 2, kc = bid & 3, k0 = kc*192;
                stageA(p.wghtd, 768, 0, k0, true, smem, tid);
                mm192f(p.W_ih + (size_t)d*4718592 + (size_t)768*3072, 3072,
                       p.wiP + (size_t)kc*49152, tile*64, k0, smem, tid);
            }
            gsync(p.bar, bid, n); n++;

            // ===== S4: LN + gates (16 blocks) =====
            if (bid < 16){
                const int b = bid;
                float* wi_sh = smem;           // 3072
                float* wh_sh = smem + 3072;    // 3072
                float* c_sh  = smem + 6144;    // 768
                float* red   = smem + 6928;    // 4
                const float mm = p.mask_p[b*128 + t];
                const float* gi = p.ln_i_g + d*3072; const float* bi = p.ln_i_b + d*3072;
                const float* gh = p.ln_h_g + d*3072; const float* bh = p.ln_h_b + d*3072;
                const float* gc = p.ln_c_g + d*768;  const float* bc = p.ln_c_b + d*768;
                const float* bias_d = p.bias + d*3072;

                float swi=0,qwi=0,swh=0,qwh=0;
                #pragma unroll
                for (int rep = 0; rep < 3; rep++){
                    int j4 = tid + rep*256;
                    int base = b*3072 + j4*4;
                    f32x4 a = {0,0,0,0};
                    f32x4 hvec = {0,0,0,0};
                    #pragma unroll
                    for (int cp = 0; cp < 4; cp++){
                        const float* s0 = p.wiP + (size_t)cp*49152 + base;
                        float2 u0 = ld2a(s0);
                        float2 u1 = ld2a(s0 + 2);
                        a.x += u0.x; a.y += u0.y; a.z += u1.x; a.w += u1.y;
                        const float* s1 = p.whP + (size_t)cp*49152 + base;
                        float2 v0 = ld2a(s1);
                        float2 v1 = ld2a(s1 + 2);
                        hvec.x += v0.x; hvec.y += v0.y; hvec.z += v1.x; hvec.w += v1.y;
                    }
                    if (d == 0){
                        f32x4 pv = *(const f32x4*)(p.pWih0 + ((size_t)b*128 + t)*3072 + j4*4);
                        a += pv;
                    } else {
                        #pragma unroll
                        for (int cp = 0; cp < 4; cp++){
                            const float* s2 = p.cwP + (size_t)cp*49152 + base;
                            float2 w0 = ld2a(s2);
                            float2 w1 = ld2a(s2 + 2);
                            a.x += w0.x; a.y += w0.y; a.z += w1.x; a.w += w1.y;
                        }
                    }
                    *(f32x4*)&wi_sh[j4*4] = a;
                    *(f32x4*)&wh_sh[j4*4] = hvec;
                    swi += a.x+a.y+a.z+a.w;
                    qwi += dot4(a,a);
                    swh += hvec.x+hvec.y+hvec.z+hvec.w;
                    qwh += dot4(hvec,hvec);
                }
                swi = bsum4(swi, red, tid);
                qwi = bsum4(qwi, red, tid);
                swh = bsum4(swh, red, tid);
                qwh = bsum4(qwh, red, tid);
                float mi = swi/3072.f, vi = fmaxf((qwi - 3072.f*mi*mi)/3071.f, 0.f);
                float mh = swh/3072.f, vh = fmaxf((qwh - 3072.f*mh*mh)/3071.f, 0.f);
                float ivi = 1.f/(sqrtf(vi + 1e-6f) + 1e-6f);
                float ivh = 1.f/(sqrtf(vh + 1e-6f) + 1e-6f);

                for (int j = tid; j < 3072; j += NTHR){
                    float pre = mm*(gi[j]*(wi_sh[j]-mi)*ivi + bi[j])
                              + mm*(gh[j]*(wh_sh[j]-mh)*ivh + bh[j])
                              + bias_d[j];
                    wi_sh[j] = pre;
                }
                __syncthreads();

                float sc=0,qc=0;
                for (int idx = tid; idx < 384; idx += NTHR){
                    int u = idx*2;
                    float2 c_old = ld2a(p.c + (size_t)d*12288 + b*768 + u);
                    float f0  = wi_sh[u],        f1  = wi_sh[u+1];
                    float i0  = wi_sh[768+u],    i1  = wi_sh[768+u+1];
                    float g0  = wi_sh[2304+u],   g1  = wi_sh[2304+u+1];
                    float c10 = fsigmoid(f0)*c_old.x + fsigmoid(i0)*ftanh(g0);
                    float c11 = fsigmoid(f1)*c_old.y + fsigmoid(i1)*ftanh(g1);
                    c10 = c10*mm + c_old.x*(1.f - mm);
                    c11 = c11*mm + c_old.y*(1.f - mm);
                    st2a(p.c + (size_t)d*12288 + b*768 + u, c10, c11);
                    c_sh[u] = c10; c_sh[u+1] = c11;
                    sc += c10 + c11; qc += c10*c10 + c11*c11;
                }
                sc = bsum4(sc, red, tid);
                qc = bsum4(qc, red, tid);
                float mc = sc/768.f, vc = fmaxf((qc - 768.f*mc*mc)/767.f, 0.f);
                float ivc = 1.f/(sqrtf(vc + 1e-6f) + 1e-6f);

                for (int idx = tid; idx < 384; idx += NTHR){
                    int u = idx*2;
                    float2 h_old = ld2a(p.h + (size_t)d*12288 + b*768 + u);
                    float o0 = wi_sh[1536+u], o1 = wi_sh[1536+u+1];
                    float l0 = (gc[u]*(c_sh[u]-mc)*ivc + bc[u])*mm;
                    float l1 = (gc[u+1]*(c_sh[u+1]-mc)*ivc + bc[u+1])*mm;
                    float h10 = fsigmoid(o0)*ftanh(l0);
                    float h11 = fsigmoid(o1)*ftanh(l1);
                    h10 = h10*mm + h_old.x*(1.f - mm);
                    h11 = h11*mm + h_old.y*(1.f - mm);
                    st2a(p.h + (size_t)d*12288 + b*768 + u, h10, h11);
                    if (d == 1){
                        float2 ov = { h10, h11 };
                        *(float2*)(p.out + ((size_t)b*128 + t)*768 + u) = ov;
                    }
                }
            }
            gsync(p.bar, bid, n); n++;
        }
    }
}

// ---------- precompute GEMM (f32 out; validated R0/R1/R5/R7 kernel) ----------
__global__ __launch_bounds__(256) void k_mm_pre(
    const float* __restrict__ Ain, const float* __restrict__ W,
    float* __restrict__ C, int ldw, int ncols)
{
    __shared__ float Ash[16][772];
    int rowbase = blockIdx.y*16;
    for (int r = 0; r < 16; r++)
        for (int i = threadIdx.x; i < 768; i += 256)
            Ash[r][i] = Ain[(size_t)(rowbase + r)*768 + i];
    __syncthreads();
    int lane = threadIdx.x & 63;
    int colq = lane & 15, rsub = lane >> 4, wq = threadIdx.x >> 6;
    int r = wq*4 + rsub;
    int col = blockIdx.x*64 + colq*4;
    float4 acc = {0.f,0.f,0.f,0.f};
    const float* Wc = W + col;
    for (int k = 0; k < 768; k += 4){
        float4 a4 = *(const float4*)&Ash[r][k];
        float4 w0 = *(const float4*)(Wc + (size_t)(k+0)*ldw);
        float4 w1 = *(const float4*)(Wc + (size_t)(k+1)*ldw);
        float4 w2 = *(const float4*)(Wc + (size_t)(k+2)*ldw);
        float4 w3 = *(const float4*)(Wc + (size_t)(k+3)*ldw);
        acc.x += a4.x*w0.x + a4.y*w1.x + a4.z*w2.x + a4.w*w3.x;
        acc.y += a4.x*w0.y + a4.y*w1.y + a4.z*w2.y + a4.w*w3.y;
        acc.z += a4.x*w0.z + a4.y*w1.z + a4.z*w2.z + a4.w*w3.z;
        acc.w += a4.x*w0.w + a4.y*w1.w + a4.z*w2.w + a4.w*w3.w;
    }
    *(float4*)(C + (size_t)(rowbase + r)*ncols + col) = acc;
}

// ---------- transpose input_q -> iqT[b][c][sq] f32 ----------
__global__ __launch_bounds__(256) void k_transq(
    const float* __restrict__ iq, float* __restrict__ iqT)
{
    __shared__ float Tsh[32][136];
    int c0 = blockIdx.x*32, b = blockIdx.y;
    for (int rep = 0; rep < 4; rep++){
        int idx = threadIdx.x + rep*256;
        int sq = idx >> 3, cq = idx & 7;
        float4 v = *(const float4*)(iq + ((size_t)b*128 + sq)*768 + c0 + cq*4);
        Tsh[cq*4+0][sq] = v.x;
        Tsh[cq*4+1][sq] = v.y;
        Tsh[cq*4+2][sq] = v.z;
        Tsh[cq*4+3][sq] = v.w;
    }
    __syncthreads();
    for (int rep = 0; rep < 4; rep++){
        int idx = threadIdx.x + rep*256;
        int cl = idx >> 5, sq4 = (idx & 31)*4;
        float4 v = *(const float4*)&Tsh[cl][sq4];
        *(float4*)(iqT + ((size_t)b*768 + c0 + cl)*128 + sq4) = v;
    }
}

extern "C" void kernel_launch(void* const* d_in, const int* in_sizes, int n_in,
                              void* d_out, int out_size, void* d_ws, size_t ws_size,
                              hipStream_t stream)
{
    (void)in_sizes; (void)n_in; (void)out_size; (void)ws_size;
    Params P;
    P.input_p = (const float*)d_in[0];
    P.mask_p  = (const float*)d_in[1];
    P.input_q = (const float*)d_in[2];
    P.mask_q  = (const float*)d_in[3];
    P.W_ih    = (const float*)d_in[4];
    P.W_hh    = (const float*)d_in[5];
    P.bias    = (const float*)d_in[6];
    P.ln_i_g  = (const float*)d_in[7];
    P.ln_i_b  = (const float*)d_in[8];
    P.ln_h_g  = (const float*)d_in[9];
    P.ln_h_b  = (const float*)d_in[10];
    P.ln_c_g  = (const float*)d_in[11];
    P.ln_c_b  = (const float*)d_in[12];
    P.Wq      = (const float*)d_in[13];
    P.Wp      = (const float*)d_in[14];
    P.Wr      = (const float*)d_in[15];
    P.w_att   = (const float*)d_in[16];
    P.b_att   = (const float*)d_in[17];
    P.out     = (float*)d_out;

    float* ws = (float*)d_ws;
    size_t off = 0;
    auto alloc = [&](size_t nfloat)->float*{
        float* r = ws + off;
        off += (nfloat + 63) & ~(size_t)63;
        return r;
    };
    P.qWq    = alloc((size_t)2*2048*768);
    P.iqT    = alloc((size_t)16*768*128);
    P.pWp0   = alloc((size_t)2048*768);
    P.pWih0  = alloc((size_t)2048*3072);
    P.h      = alloc(24576);
    P.c      = alloc(24576);          // contiguous after h
    P.sP     = alloc((size_t)8*16*768);
    P.whP    = alloc((size_t)4*16*3072);
    P.cwP    = alloc((size_t)4*16*3072);
    P.wiP    = alloc((size_t)4*16*3072);
    P.wghtd  = alloc(12288);
    P.escore = alloc(2048);
    P.bar    = (unsigned*)alloc(2048);

    hipMemsetAsync((void*)P.bar, 0, 2048*sizeof(unsigned), stream);
    k_mm_pre<<<dim3(12,128), 256, 0, stream>>>(P.input_q, P.Wq, P.qWq, 768, 768);
    k_mm_pre<<<dim3(12,128), 256, 0, stream>>>(P.input_q, P.Wq + (size_t)589824,
                                               P.qWq + (size_t)2048*768, 768, 768);
    k_mm_pre<<<dim3(12,128), 256, 0, stream>>>(P.input_p, P.Wp, P.pWp0, 768, 768);
    k_mm_pre<<<dim3(48,128), 256, 0, stream>>>(P.input_p, P.W_ih, P.pWih0, 3072, 3072);
    k_transq<<<dim3(24,16), 256, 0, stream>>>(P.input_q, P.iqT);
    coop_kernel<<<dim3(NBLK), dim3(NTHR), 0, stream>>>(P);
}